// Round 3
// baseline (906.989 us; speedup 1.0000x reference)
//
#include <hip/hip_runtime.h>
#include <hip/hip_bf16.h>
#include <math.h>

#define S_LEN 2048
#define B_SZ 2
#define DMODEL 1024
#define NH 16
#define DK 64
#define QKVN 3072          // fused QKV output width
#define SM_SHIFT 8.0f      // constant softmax shift: exp(s-8); exact after /l

typedef __attribute__((ext_vector_type(8))) short bf16x8;
typedef __attribute__((ext_vector_type(4))) float f32x4;

__device__ inline short f2bf(float f) {
    __hip_bfloat16 h = __float2bfloat16(f);
    return __builtin_bit_cast(short, h);
}
__device__ inline float bf2f(short s) {
    unsigned int u = ((unsigned int)(unsigned short)s) << 16;
    return __builtin_bit_cast(float, u);
}
__device__ inline f32x4 mfma16(bf16x8 a, bf16x8 b, f32x4 c) {
    return __builtin_amdgcn_mfma_f32_16x16x32_bf16(a, b, c, 0, 0, 0);
}
// async global->LDS, 16B per lane; LDS dest = wave-uniform base + lane*16
__device__ inline void gl_lds16(const void* g, void* l) {
    __builtin_amdgcn_global_load_lds(
        (const __attribute__((address_space(1))) void*)g,
        (__attribute__((address_space(3))) void*)l, 16, 0, 0);
}

// ---------------------------------------------------------------------------
// fp32 -> bf16 elementwise convert (x)
// ---------------------------------------------------------------------------
__global__ __launch_bounds__(256) void cvt_bf16(const float* __restrict__ in,
                                                short* __restrict__ out, int n4) {
    int i = blockIdx.x * 256 + threadIdx.x;
    if (i < n4) {
        float4 v = *(const float4*)&in[(size_t)i * 4];
        short4 o = { f2bf(v.x), f2bf(v.y), f2bf(v.z), f2bf(v.w) };
        *(short4*)&out[(size_t)i * 4] = o;
    }
}

// ---------------------------------------------------------------------------
// Weight transpose+convert: W fp32 [K=1024][N=1024] -> Wt bf16 [N][K]
// ---------------------------------------------------------------------------
__global__ __launch_bounds__(256) void wtrans(const float* __restrict__ W,
                                              short* __restrict__ Wt) {
    __shared__ __align__(16) short T[64][72];
    const int k0 = blockIdx.x * 64, n0 = blockIdx.y * 64;
    const int tid = threadIdx.x;
#pragma unroll
    for (int i = 0; i < 4; ++i) {
        int idx = tid + i * 256;          // 64 k-rows x 16 float4
        int kr = idx >> 4, n4 = idx & 15;
        float4 v = *(const float4*)&W[(size_t)(k0 + kr) * DMODEL + n0 + n4 * 4];
        short4 o = { f2bf(v.x), f2bf(v.y), f2bf(v.z), f2bf(v.w) };
        *(short4*)&T[kr][n4 * 4] = o;
    }
    __syncthreads();
#pragma unroll
    for (int i = 0; i < 2; ++i) {
        int idx = tid + i * 256;          // 64 n-rows x 8 chunks(8 shorts)
        int n = idx >> 3, c8 = idx & 7;
        short v[8];
#pragma unroll
        for (int j = 0; j < 8; ++j) v[j] = T[c8 * 8 + j][n];
        *(int4*)&Wt[(size_t)(n0 + n) * DMODEL + k0 + c8 * 8] = *(int4*)v;
    }
}

// ---------------------------------------------------------------------------
// concat bias [bq|bk|bv] -> cbias[3072]
// ---------------------------------------------------------------------------
__global__ __launch_bounds__(256) void cbias_cat(const float* __restrict__ bq,
                                                 const float* __restrict__ bk,
                                                 const float* __restrict__ bv,
                                                 float* __restrict__ cb) {
    int i = blockIdx.x * 256 + threadIdx.x;
    if (i < QKVN)
        cb[i] = i < 1024 ? bq[i] : (i < 2048 ? bk[i - 1024] : bv[i - 2048]);
}

// ---------------------------------------------------------------------------
// 128x128-tile MFMA GEMM (m97 structure): C[M,N] = A[M,K] @ Bt[N,K]^T + bias.
// BK=64, global_load_lds width-16 staging. 4 waves (2x2), 64x64 per wave.
// ---------------------------------------------------------------------------
template <bool OUT_BF16>
__global__ __launch_bounds__(256) void gemm128(
    const short* __restrict__ A, const short* __restrict__ Bt,
    const float* __restrict__ bias, void* __restrict__ Cout,
    int M, int N, int K) {
    __shared__ __align__(16) short As[128][64];   // linear: required by gl_lds16
    __shared__ __align__(16) short Bs[128][64];
    const int row0 = blockIdx.y * 128, col0 = blockIdx.x * 128;
    const int tid = threadIdx.x;
    const int w = tid >> 6, l = tid & 63, lm = l & 15, quad = l >> 4;
    const int wm = (w >> 1) * 64, wn = (w & 1) * 64;
    const int lrow = tid >> 3, lc8 = tid & 7;     // 32 rows x 8 chunks per issue
    f32x4 acc[4][4] = {};

    for (int k0 = 0; k0 < K; k0 += 64) {
        __syncthreads();
#pragma unroll
        for (int i = 0; i < 4; ++i)               // A: 128 rows, 32/issue
            gl_lds16(&A[(size_t)(row0 + i * 32 + lrow) * K + k0 + lc8 * 8],
                     (short*)As + (i * 32 + w * 8) * 64);
#pragma unroll
        for (int i = 0; i < 4; ++i)               // B: 128 rows
            gl_lds16(&Bt[(size_t)(col0 + i * 32 + lrow) * K + k0 + lc8 * 8],
                     (short*)Bs + (i * 32 + w * 8) * 64);
        __syncthreads();                          // drains vmcnt before barrier
#pragma unroll
        for (int kc = 0; kc < 2; ++kc) {
            bf16x8 a[4], b[4];
#pragma unroll
            for (int mi = 0; mi < 4; ++mi)
                a[mi] = *(const bf16x8*)&As[wm + mi * 16 + lm][kc * 32 + quad * 8];
#pragma unroll
            for (int ni = 0; ni < 4; ++ni)
                b[ni] = *(const bf16x8*)&Bs[wn + ni * 16 + lm][kc * 32 + quad * 8];
#pragma unroll
            for (int mi = 0; mi < 4; ++mi)
#pragma unroll
                for (int ni = 0; ni < 4; ++ni)
                    acc[mi][ni] = mfma16(a[mi], b[ni], acc[mi][ni]);
        }
    }
#pragma unroll
    for (int mi = 0; mi < 4; ++mi)
#pragma unroll
        for (int ni = 0; ni < 4; ++ni) {
            int col = col0 + wn + ni * 16 + lm;
            float bs = bias[col];
#pragma unroll
            for (int r = 0; r < 4; ++r) {
                int row = row0 + wm + mi * 16 + quad * 4 + r;
                float v = acc[mi][ni][r] + bs;
                if (OUT_BF16)
                    ((short*)Cout)[(size_t)row * N + col] = f2bf(v);
                else
                    ((float*)Cout)[(size_t)row * N + col] = v;
            }
        }
}

// ---------------------------------------------------------------------------
// V transpose (per head): QKV bf16 [b][s][3072] (V at col 2048) ->
// Vt bf16 [bh][64 d][2048 s]
// ---------------------------------------------------------------------------
__global__ __launch_bounds__(256) void vtrans(const short* __restrict__ QKV,
                                              short* __restrict__ Vt) {
    __shared__ __align__(16) short T[64][72];
    const int bh = blockIdx.y, b = bh >> 4, h = bh & 15;
    const int s0 = blockIdx.x * 64;
    const int tid = threadIdx.x;
#pragma unroll
    for (int i = 0; i < 2; ++i) {
        int idx = tid + i * 256;          // 64 token-rows x 8 chunks
        int r = idx >> 3, c8 = idx & 7;
        *(int4*)&T[r][c8 * 8] =
            *(const int4*)&QKV[((size_t)(b * S_LEN + s0 + r)) * QKVN + 2048 + h * DK + c8 * 8];
    }
    __syncthreads();
#pragma unroll
    for (int i = 0; i < 2; ++i) {
        int idx = tid + i * 256;          // 64 d-rows x 8 chunks
        int d = idx >> 3, c8 = idx & 7;
        short v[8];
#pragma unroll
        for (int j = 0; j < 8; ++j) v[j] = T[c8 * 8 + j][d];
        *(int4*)&Vt[((size_t)(bh * DK + d)) * S_LEN + s0 + c8 * 8] = *(int4*)v;
    }
}

// ---------------------------------------------------------------------------
// first nonpad token index per batch
// ---------------------------------------------------------------------------
__global__ __launch_bounds__(256) void fnp_scan(const int* __restrict__ tok,
                                                int* __restrict__ fnp) {
    __shared__ int mn;
    const int b = blockIdx.x;
    if (threadIdx.x == 0) mn = S_LEN;
    __syncthreads();
    int loc = S_LEN;
    for (int s = threadIdx.x; s < S_LEN; s += 256)
        if (tok[b * S_LEN + s] != 0) loc = min(loc, s);
    atomicMin(&mn, loc);
    __syncthreads();
    if (threadIdx.x == 0) fnp[b] = mn;
}

// ---------------------------------------------------------------------------
// Pass A (no-max softmax): l = sum over causal band of exp(s - 8).
// No running max, no per-tile reductions; one 4-step shuffle at end of row.
// ---------------------------------------------------------------------------
__global__ __launch_bounds__(256) void flash_lsum(
    const short* __restrict__ QKV, const int* __restrict__ tok,
    float* __restrict__ Lrow) {
    const int bh = blockIdx.y, b = bh >> 4, h = bh & 15;
    const int qt = blockIdx.x, q0 = qt * 64;
    const int tid = threadIdx.x;
    const int w = tid >> 6, l = tid & 63, lm = l & 15, quad = l >> 4;
    __shared__ __align__(16) short Qs[64][72];
    __shared__ __align__(16) short Ks[64][72];
    __shared__ float padf[64];

#pragma unroll
    for (int i = 0; i < 2; ++i) {
        int idx = tid + i * 256;
        int r = idx >> 3, c8 = idx & 7;
        *(int4*)&Qs[r][c8 * 8] =
            *(const int4*)&QKV[((size_t)(b * S_LEN + q0 + r)) * QKVN + h * DK + c8 * 8];
    }

    float lsum[4] = {0.f, 0.f, 0.f, 0.f};

    for (int kt = 0; kt <= qt; ++kt) {
        __syncthreads();
#pragma unroll
        for (int i = 0; i < 2; ++i) {
            int idx = tid + i * 256;
            int r = idx >> 3, c8 = idx & 7;
            *(int4*)&Ks[r][c8 * 8] =
                *(const int4*)&QKV[((size_t)(b * S_LEN + kt * 64 + r)) * QKVN + 1024 + h * DK + c8 * 8];
        }
        if (tid < 64) padf[tid] = (tok[b * S_LEN + kt * 64 + tid] == 0) ? 1.f : 0.f;
        __syncthreads();

#pragma unroll
        for (int nt = 0; nt < 4; ++nt) {
            f32x4 acc = {0.f, 0.f, 0.f, 0.f};
#pragma unroll
            for (int kc = 0; kc < 2; ++kc) {
                bf16x8 a = *(const bf16x8*)&Qs[w * 16 + lm][kc * 32 + quad * 8];
                bf16x8 bb = *(const bf16x8*)&Ks[nt * 16 + lm][kc * 32 + quad * 8];
                acc = mfma16(a, bb, acc);
            }
            int kcol = kt * 64 + nt * 16 + lm;
            bool pad = padf[nt * 16 + lm] != 0.f;
#pragma unroll
            for (int r = 0; r < 4; ++r) {
                int qrow = q0 + w * 16 + quad * 4 + r;
                bool msk = pad || (kcol > qrow);
                lsum[r] += msk ? 0.f : __expf(acc[r] * 0.125f - SM_SHIFT);
            }
        }
    }

#pragma unroll
    for (int off = 1; off < 16; off <<= 1)
#pragma unroll
        for (int r = 0; r < 4; ++r) lsum[r] += __shfl_xor(lsum[r], off);

    if (lm == 0) {
#pragma unroll
        for (int r = 0; r < 4; ++r)
            Lrow[(size_t)bh * S_LEN + q0 + w * 16 + quad * 4 + r] = lsum[r];
    }
}

// ---------------------------------------------------------------------------
// attn scores, fully parallel over (qt,kt,bh). Lower/diag: S via MFMA,
// p = exp(s-8)/l, route through fp32 LDS tile, cooperative float4 stores
// (256B segments). Strict upper: write zeros (absorbs fill_upper).
// ---------------------------------------------------------------------------
__global__ __launch_bounds__(256) void attn_scores(
    const short* __restrict__ QKV, const int* __restrict__ tok,
    const float* __restrict__ Lrow, float* __restrict__ attn) {
    const int bh = blockIdx.y, b = bh >> 4, h = bh & 15;
    const int qt = blockIdx.x >> 5, kt = blockIdx.x & 31;
    const int q0 = qt * 64, k0 = kt * 64;
    const int tid = threadIdx.x;
    float* tileb = attn + ((size_t)bh * S_LEN + q0) * S_LEN + k0;

    if (kt > qt) {                       // causal-masked tile: zeros only
        float4 z = {0.f, 0.f, 0.f, 0.f};
#pragma unroll
        for (int i = 0; i < 4; ++i) {
            int c = tid + i * 256;       // 64 rows x 16 float4
            int row = c >> 4, c4 = c & 15;
            *(float4*)&tileb[(size_t)row * S_LEN + c4 * 4] = z;
        }
        return;
    }

    const int w = tid >> 6, l = tid & 63, lm = l & 15, quad = l >> 4;
    __shared__ __align__(16) short Qs[64][72];
    __shared__ __align__(16) short Ks[64][72];
    __shared__ __align__(16) float Ps[64][68];
    __shared__ float padf[64];
    __shared__ float sinv[64];

#pragma unroll
    for (int i = 0; i < 2; ++i) {
        int idx = tid + i * 256;
        int r = idx >> 3, c8 = idx & 7;
        *(int4*)&Qs[r][c8 * 8] =
            *(const int4*)&QKV[((size_t)(b * S_LEN + q0 + r)) * QKVN + h * DK + c8 * 8];
        *(int4*)&Ks[r][c8 * 8] =
            *(const int4*)&QKV[((size_t)(b * S_LEN + k0 + r)) * QKVN + 1024 + h * DK + c8 * 8];
    }
    if (tid < 64) {
        padf[tid] = (tok[b * S_LEN + k0 + tid] == 0) ? 1.f : 0.f;
        sinv[tid] = 1.f / Lrow[(size_t)bh * S_LEN + q0 + tid];
    }
    __syncthreads();

#pragma unroll
    for (int nt = 0; nt < 4; ++nt) {
        f32x4 acc = {0.f, 0.f, 0.f, 0.f};
#pragma unroll
        for (int kc = 0; kc < 2; ++kc) {
            bf16x8 a = *(const bf16x8*)&Qs[w * 16 + lm][kc * 32 + quad * 8];
            bf16x8 bb = *(const bf16x8*)&Ks[nt * 16 + lm][kc * 32 + quad * 8];
            acc = mfma16(a, bb, acc);
        }
        int kcol = k0 + nt * 16 + lm;
        bool pad = padf[nt * 16 + lm] != 0.f;
#pragma unroll
        for (int r = 0; r < 4; ++r) {
            int trow = w * 16 + quad * 4 + r;
            bool msk = pad || (kcol > q0 + trow);
            Ps[trow][nt * 16 + lm] =
                msk ? 0.f : __expf(acc[r] * 0.125f - SM_SHIFT) * sinv[trow];
        }
    }
    __syncthreads();
#pragma unroll
    for (int i = 0; i < 4; ++i) {
        int c = tid + i * 256;           // 64 rows x 16 float4
        int row = c >> 4, c4 = c & 15;
        *(float4*)&tileb[(size_t)row * S_LEN + c4 * 4] = *(const float4*)&Ps[row][c4 * 4];
    }
}

// ---------------------------------------------------------------------------
// ctx = attn @ V: batched band-GEMM per (qt, bh). Stages fp32 attn tile ->
// bf16 LDS (same rounding as the old fused PV), Vt tile -> LDS, 8 MFMA/wave
// per kt. No exp/stores in the loop.
// ---------------------------------------------------------------------------
__global__ __launch_bounds__(256) void pv_gemm(
    const float* __restrict__ attn, const short* __restrict__ Vt,
    short* __restrict__ ctxb) {
    const int bh = blockIdx.y, b = bh >> 4, h = bh & 15;
    const int qt = blockIdx.x, q0 = qt * 64;
    const int tid = threadIdx.x;
    const int w = tid >> 6, l = tid & 63, lm = l & 15, quad = l >> 4;
    __shared__ __align__(16) short As[64][72];   // P bf16
    __shared__ __align__(16) short Bs[64][72];   // V^T [d][k]
    f32x4 oacc[4] = {};

    for (int kt = 0; kt <= qt; ++kt) {
        __syncthreads();
#pragma unroll
        for (int i = 0; i < 4; ++i) {            // attn tile: 64 rows x 16 float4
            int c = tid + i * 256;
            int row = c >> 4, c4 = c & 15;
            float4 v = *(const float4*)&attn[((size_t)bh * S_LEN + q0 + row) * S_LEN +
                                             kt * 64 + c4 * 4];
            short4 o = { f2bf(v.x), f2bf(v.y), f2bf(v.z), f2bf(v.w) };
            *(short4*)&As[row][c4 * 4] = o;
        }
#pragma unroll
        for (int i = 0; i < 2; ++i) {            // Vt tile: 64 d-rows x 8 chunks
            int idx = tid + i * 256;
            int r = idx >> 3, c8 = idx & 7;
            *(int4*)&Bs[r][c8 * 8] =
                *(const int4*)&Vt[((size_t)(bh * DK + r)) * S_LEN + kt * 64 + c8 * 8];
        }
        __syncthreads();
#pragma unroll
        for (int kc = 0; kc < 2; ++kc) {
            bf16x8 a = *(const bf16x8*)&As[w * 16 + lm][kc * 32 + quad * 8];
#pragma unroll
            for (int dt = 0; dt < 4; ++dt) {
                bf16x8 bv = *(const bf16x8*)&Bs[dt * 16 + lm][kc * 32 + quad * 8];
                oacc[dt] = mfma16(a, bv, oacc[dt]);
            }
        }
    }

#pragma unroll
    for (int dt = 0; dt < 4; ++dt)
#pragma unroll
        for (int r = 0; r < 4; ++r) {
            int qrow = q0 + w * 16 + quad * 4 + r;
            ctxb[((size_t)(b * S_LEN + qrow)) * DMODEL + h * DK + dt * 16 + lm] =
                f2bf(oacc[dt][r]);
        }
}

// ---------------------------------------------------------------------------
// Fully-masked rows (q < first-nonpad): attn row = 1/2048 (all heads),
// ctx row = mean(V). Rare/usually-empty; blocks early-out.
// ---------------------------------------------------------------------------
__global__ __launch_bounds__(256) void fix_fullmask(
    const int* __restrict__ fnp, const short* __restrict__ QKV,
    float* __restrict__ attn, short* __restrict__ ctxb) {
    const int b = blockIdx.x >> 11, q = blockIdx.x & 2047;
    if (q >= fnp[b]) return;
    const float u = 1.f / (float)S_LEN;
    float4 uu = {u, u, u, u};
    for (int i = threadIdx.x; i < NH * (S_LEN / 4); i += 256) {
        int h = i / (S_LEN / 4), c4 = i % (S_LEN / 4);
        *(float4*)&attn[(((size_t)(b * NH + h) * S_LEN + q)) * S_LEN + c4 * 4] = uu;
    }
    for (int d = threadIdx.x; d < DMODEL; d += 256) {
        float sv = 0.f;
        for (int s = 0; s < S_LEN; ++s)
            sv += bf2f(QKV[((size_t)(b * S_LEN + s)) * QKVN + 2048 + d]);
        ctxb[((size_t)(b * S_LEN + q)) * DMODEL + d] = f2bf(sv * u);
    }
}

extern "C" void kernel_launch(void* const* d_in, const int* in_sizes, int n_in,
                              void* d_out, int out_size, void* d_ws, size_t ws_size,
                              hipStream_t stream) {
    const float* x  = (const float*)d_in[0];
    const int*  tok = (const int*)d_in[1];
    const float* wq = (const float*)d_in[2];
    const float* bq = (const float*)d_in[3];
    const float* wk = (const float*)d_in[4];
    const float* bk = (const float*)d_in[5];
    const float* wv = (const float*)d_in[6];
    const float* bv = (const float*)d_in[7];
    const float* wo = (const float*)d_in[8];
    const float* bo = (const float*)d_in[9];

    float* out  = (float*)d_out;
    float* attn = out + (size_t)B_SZ * S_LEN * DMODEL;

    const size_t NTOK = (size_t)B_SZ * S_LEN;        // 4096
    const size_t NE   = NTOK * DMODEL;               // 4,194,304
    const size_t WSZ  = (size_t)DMODEL * DMODEL;     // 1M elements
    short* xb    = (short*)d_ws;                     // [4096][1024]
    short* Wt3   = xb + NE;                          // [3072][1024]
    short* Wto   = Wt3 + 3 * WSZ;                    // [1024][1024]
    short* QKVb  = Wto + WSZ;                        // [4096][3072]
    short* Vt    = QKVb + NTOK * QKVN;               // [32][64][2048]
    short* ctxb  = Vt + NE;                          // [4096][1024]
    float* cbias = (float*)(ctxb + NE);              // [3072]
    float* Lrow  = cbias + QKVN;                     // [32][2048]
    int*   fnp   = (int*)(Lrow + (size_t)B_SZ * NH * S_LEN);

    dim3 blk(256);

    cvt_bf16<<<dim3((int)(NE / 4 / 256)), blk, 0, stream>>>(x, xb, (int)(NE / 4));
    wtrans<<<dim3(16, 16), blk, 0, stream>>>(wq, Wt3 + 0 * WSZ);
    wtrans<<<dim3(16, 16), blk, 0, stream>>>(wk, Wt3 + 1 * WSZ);
    wtrans<<<dim3(16, 16), blk, 0, stream>>>(wv, Wt3 + 2 * WSZ);
    wtrans<<<dim3(16, 16), blk, 0, stream>>>(wo, Wto);
    cbias_cat<<<dim3(QKVN / 256), blk, 0, stream>>>(bq, bk, bv, cbias);

    gemm128<true><<<dim3(QKVN / 128, (int)(NTOK / 128)), blk, 0, stream>>>(
        xb, Wt3, cbias, QKVb, (int)NTOK, QKVN, DMODEL);

    vtrans<<<dim3(S_LEN / 64, B_SZ * NH), blk, 0, stream>>>(QKVb, Vt);
    fnp_scan<<<dim3(B_SZ), blk, 0, stream>>>(tok, fnp);

    flash_lsum<<<dim3(S_LEN / 64, B_SZ * NH), blk, 0, stream>>>(QKVb, tok, Lrow);

    attn_scores<<<dim3((S_LEN / 64) * (S_LEN / 64), B_SZ * NH), blk, 0, stream>>>(
        QKVb, tok, Lrow, attn);
    pv_gemm<<<dim3(S_LEN / 64, B_SZ * NH), blk, 0, stream>>>(attn, Vt, ctxb);
    fix_fullmask<<<dim3(B_SZ * S_LEN), blk, 0, stream>>>(fnp, QKVb, attn, ctxb);

    gemm128<false><<<dim3(DMODEL / 128, (int)(NTOK / 128)), blk, 0, stream>>>(
        ctxb, Wto, bo, out, (int)NTOK, DMODEL, DMODEL);
}

// Round 4
// 828.438 us; speedup vs baseline: 1.0948x; 1.0948x over previous
//
#include <hip/hip_runtime.h>
#include <hip/hip_bf16.h>
#include <math.h>

#define S_LEN 2048
#define B_SZ 2
#define DMODEL 1024
#define NH 16
#define DK 64
#define QKVN 3072          // fused QKV output width
#define SM_SHIFT 8.0f      // constant softmax shift: exp(s-8); exact after /l

typedef __attribute__((ext_vector_type(8))) short bf16x8;
typedef __attribute__((ext_vector_type(4))) float f32x4;

__device__ inline short f2bf(float f) {
    __hip_bfloat16 h = __float2bfloat16(f);
    return __builtin_bit_cast(short, h);
}
__device__ inline float bf2f(short s) {
    unsigned int u = ((unsigned int)(unsigned short)s) << 16;
    return __builtin_bit_cast(float, u);
}
__device__ inline f32x4 mfma16(bf16x8 a, bf16x8 b, f32x4 c) {
    return __builtin_amdgcn_mfma_f32_16x16x32_bf16(a, b, c, 0, 0, 0);
}
// async global->LDS, 16B per lane; LDS dest = wave-uniform base + lane*16
__device__ inline void gl_lds16(const void* g, void* l) {
    __builtin_amdgcn_global_load_lds(
        (const __attribute__((address_space(1))) void*)g,
        (__attribute__((address_space(3))) void*)l, 16, 0, 0);
}

// ---------------------------------------------------------------------------
// fp32 -> bf16 elementwise convert (x)
// ---------------------------------------------------------------------------
__global__ __launch_bounds__(256) void cvt_bf16(const float* __restrict__ in,
                                                short* __restrict__ out, int n4) {
    int i = blockIdx.x * 256 + threadIdx.x;
    if (i < n4) {
        float4 v = *(const float4*)&in[(size_t)i * 4];
        short4 o = { f2bf(v.x), f2bf(v.y), f2bf(v.z), f2bf(v.w) };
        *(short4*)&out[(size_t)i * 4] = o;
    }
}

// ---------------------------------------------------------------------------
// Weight transpose+convert: W fp32 [K=1024][N=1024] -> Wt bf16 [N][K]
// ---------------------------------------------------------------------------
__global__ __launch_bounds__(256) void wtrans(const float* __restrict__ W,
                                              short* __restrict__ Wt) {
    __shared__ __align__(16) short T[64][72];
    const int k0 = blockIdx.x * 64, n0 = blockIdx.y * 64;
    const int tid = threadIdx.x;
#pragma unroll
    for (int i = 0; i < 4; ++i) {
        int idx = tid + i * 256;          // 64 k-rows x 16 float4
        int kr = idx >> 4, n4 = idx & 15;
        float4 v = *(const float4*)&W[(size_t)(k0 + kr) * DMODEL + n0 + n4 * 4];
        short4 o = { f2bf(v.x), f2bf(v.y), f2bf(v.z), f2bf(v.w) };
        *(short4*)&T[kr][n4 * 4] = o;
    }
    __syncthreads();
#pragma unroll
    for (int i = 0; i < 2; ++i) {
        int idx = tid + i * 256;          // 64 n-rows x 8 chunks(8 shorts)
        int n = idx >> 3, c8 = idx & 7;
        short v[8];
#pragma unroll
        for (int j = 0; j < 8; ++j) v[j] = T[c8 * 8 + j][n];
        *(int4*)&Wt[(size_t)(n0 + n) * DMODEL + k0 + c8 * 8] = *(int4*)v;
    }
}

// ---------------------------------------------------------------------------
// concat bias [bq|bk|bv] -> cbias[3072]
// ---------------------------------------------------------------------------
__global__ __launch_bounds__(256) void cbias_cat(const float* __restrict__ bq,
                                                 const float* __restrict__ bk,
                                                 const float* __restrict__ bv,
                                                 float* __restrict__ cb) {
    int i = blockIdx.x * 256 + threadIdx.x;
    if (i < QKVN)
        cb[i] = i < 1024 ? bq[i] : (i < 2048 ? bk[i - 1024] : bv[i - 2048]);
}

// ---------------------------------------------------------------------------
// 128x128-tile MFMA GEMM (m97 structure): C[M,N] = A[M,K] @ Bt[N,K]^T + bias.
// BK=64, global_load_lds width-16 staging. 4 waves (2x2), 64x64 per wave.
// ---------------------------------------------------------------------------
__global__ __launch_bounds__(256) void gemm128(
    const short* __restrict__ A, const short* __restrict__ Bt,
    const float* __restrict__ bias, short* __restrict__ C,
    int M, int N, int K) {
    __shared__ __align__(16) short As[128][64];   // linear: required by gl_lds16
    __shared__ __align__(16) short Bs[128][64];
    const int row0 = blockIdx.y * 128, col0 = blockIdx.x * 128;
    const int tid = threadIdx.x;
    const int w = tid >> 6, l = tid & 63, lm = l & 15, quad = l >> 4;
    const int wm = (w >> 1) * 64, wn = (w & 1) * 64;
    const int lrow = tid >> 3, lc8 = tid & 7;     // 32 rows x 8 chunks per issue
    f32x4 acc[4][4] = {};

    for (int k0 = 0; k0 < K; k0 += 64) {
        __syncthreads();
#pragma unroll
        for (int i = 0; i < 4; ++i)               // A: 128 rows, 32/issue
            gl_lds16(&A[(size_t)(row0 + i * 32 + lrow) * K + k0 + lc8 * 8],
                     (short*)As + (i * 32 + w * 8) * 64);
#pragma unroll
        for (int i = 0; i < 4; ++i)               // B: 128 rows
            gl_lds16(&Bt[(size_t)(col0 + i * 32 + lrow) * K + k0 + lc8 * 8],
                     (short*)Bs + (i * 32 + w * 8) * 64);
        __syncthreads();                          // drains vmcnt before barrier
#pragma unroll
        for (int kc = 0; kc < 2; ++kc) {
            bf16x8 a[4], b[4];
#pragma unroll
            for (int mi = 0; mi < 4; ++mi)
                a[mi] = *(const bf16x8*)&As[wm + mi * 16 + lm][kc * 32 + quad * 8];
#pragma unroll
            for (int ni = 0; ni < 4; ++ni)
                b[ni] = *(const bf16x8*)&Bs[wn + ni * 16 + lm][kc * 32 + quad * 8];
#pragma unroll
            for (int mi = 0; mi < 4; ++mi)
#pragma unroll
                for (int ni = 0; ni < 4; ++ni)
                    acc[mi][ni] = mfma16(a[mi], b[ni], acc[mi][ni]);
        }
    }
#pragma unroll
    for (int mi = 0; mi < 4; ++mi)
#pragma unroll
        for (int ni = 0; ni < 4; ++ni) {
            int col = col0 + wn + ni * 16 + lm;
            float bs = bias[col];
#pragma unroll
            for (int r = 0; r < 4; ++r) {
                int row = row0 + wm + mi * 16 + quad * 4 + r;
                C[(size_t)row * N + col] = f2bf(acc[mi][ni][r] + bs);
            }
        }
}

// ---------------------------------------------------------------------------
// 64x64-tile bf16 MFMA GEMM, fp32 out (output projection; 4 blocks/CU).
// ---------------------------------------------------------------------------
__global__ __launch_bounds__(256) void gemm64(
    const short* __restrict__ A, const short* __restrict__ Bt,
    const float* __restrict__ bias, float* __restrict__ Cout,
    int M, int N, int K) {
    __shared__ __align__(16) short As[64][72];
    __shared__ __align__(16) short Bs[64][72];
    const int row0 = blockIdx.y * 64, col0 = blockIdx.x * 64;
    const int tid = threadIdx.x;
    const int w = tid >> 6, l = tid & 63, lm = l & 15, quad = l >> 4;
    const int wm = (w >> 1) * 32, wn = (w & 1) * 32;
    f32x4 acc[2][2] = {};

    for (int k0 = 0; k0 < K; k0 += 64) {
        __syncthreads();
#pragma unroll
        for (int i = 0; i < 2; ++i) {
            int idx = tid + i * 256;
            int r = idx >> 3, c8 = idx & 7;
            *(int4*)&As[r][c8 * 8] = *(const int4*)&A[(size_t)(row0 + r) * K + k0 + c8 * 8];
            *(int4*)&Bs[r][c8 * 8] = *(const int4*)&Bt[(size_t)(col0 + r) * K + k0 + c8 * 8];
        }
        __syncthreads();
#pragma unroll
        for (int kc = 0; kc < 2; ++kc) {
            bf16x8 a0 = *(const bf16x8*)&As[wm + lm][kc * 32 + quad * 8];
            bf16x8 a1 = *(const bf16x8*)&As[wm + 16 + lm][kc * 32 + quad * 8];
            bf16x8 b0 = *(const bf16x8*)&Bs[wn + lm][kc * 32 + quad * 8];
            bf16x8 b1 = *(const bf16x8*)&Bs[wn + 16 + lm][kc * 32 + quad * 8];
            acc[0][0] = mfma16(a0, b0, acc[0][0]);
            acc[0][1] = mfma16(a0, b1, acc[0][1]);
            acc[1][0] = mfma16(a1, b0, acc[1][0]);
            acc[1][1] = mfma16(a1, b1, acc[1][1]);
        }
    }
#pragma unroll
    for (int mi = 0; mi < 2; ++mi)
#pragma unroll
        for (int ni = 0; ni < 2; ++ni)
#pragma unroll
            for (int r = 0; r < 4; ++r) {
                int row = row0 + wm + mi * 16 + quad * 4 + r;
                int col = col0 + wn + ni * 16 + lm;
                Cout[(size_t)row * N + col] = acc[mi][ni][r] + bias[col];
            }
}

// ---------------------------------------------------------------------------
// V transpose (per head): QKV bf16 [b][s][3072] (V at col 2048) ->
// Vt bf16 [bh][64 d][2048 s]
// ---------------------------------------------------------------------------
__global__ __launch_bounds__(256) void vtrans(const short* __restrict__ QKV,
                                              short* __restrict__ Vt) {
    __shared__ __align__(16) short T[64][72];
    const int bh = blockIdx.y, b = bh >> 4, h = bh & 15;
    const int s0 = blockIdx.x * 64;
    const int tid = threadIdx.x;
#pragma unroll
    for (int i = 0; i < 2; ++i) {
        int idx = tid + i * 256;          // 64 token-rows x 8 chunks
        int r = idx >> 3, c8 = idx & 7;
        *(int4*)&T[r][c8 * 8] =
            *(const int4*)&QKV[((size_t)(b * S_LEN + s0 + r)) * QKVN + 2048 + h * DK + c8 * 8];
    }
    __syncthreads();
#pragma unroll
    for (int i = 0; i < 2; ++i) {
        int idx = tid + i * 256;          // 64 d-rows x 8 chunks
        int d = idx >> 3, c8 = idx & 7;
        short v[8];
#pragma unroll
        for (int j = 0; j < 8; ++j) v[j] = T[c8 * 8 + j][d];
        *(int4*)&Vt[((size_t)(bh * DK + d)) * S_LEN + s0 + c8 * 8] = *(int4*)v;
    }
}

// ---------------------------------------------------------------------------
// first nonpad token index per batch
// ---------------------------------------------------------------------------
__global__ __launch_bounds__(256) void fnp_scan(const int* __restrict__ tok,
                                                int* __restrict__ fnp) {
    __shared__ int mn;
    const int b = blockIdx.x;
    if (threadIdx.x == 0) mn = S_LEN;
    __syncthreads();
    int loc = S_LEN;
    for (int s = threadIdx.x; s < S_LEN; s += 256)
        if (tok[b * S_LEN + s] != 0) loc = min(loc, s);
    atomicMin(&mn, loc);
    __syncthreads();
    if (threadIdx.x == 0) fnp[b] = mn;
}

// ---------------------------------------------------------------------------
// zero Lrow [32][2048]
// ---------------------------------------------------------------------------
__global__ __launch_bounds__(256) void lzero(float* __restrict__ L) {
    float4 z = {0.f, 0.f, 0.f, 0.f};
    *(float4*)&L[(size_t)(blockIdx.x * 256 + threadIdx.x) * 4] = z;
}

// ---------------------------------------------------------------------------
// Parallel l-sum: grid (qt*32+kt, bh). Band tiles: QK^T via MFMA,
// p = exp(s-8), intra-tile row-sum (4-step shuffle over the 16 lm lanes),
// atomicAdd into Lrow. Strict-upper tiles: write attn zeros instead
// (absorbs fill_upper into otherwise-idle blocks). No serial loop, no
// load imbalance, Q+K working set (17 MB) is L3-resident.
// ---------------------------------------------------------------------------
__global__ __launch_bounds__(256) void lsum_par(
    const short* __restrict__ QKV, const int* __restrict__ tok,
    float* __restrict__ Lrow, float* __restrict__ attn) {
    const int bh = blockIdx.y, b = bh >> 4, h = bh & 15;
    const int qt = blockIdx.x >> 5, kt = blockIdx.x & 31;
    const int q0 = qt * 64, k0 = kt * 64;
    const int tid = threadIdx.x;

    if (kt > qt) {                       // causal-masked tile: zeros only
        float4 z = {0.f, 0.f, 0.f, 0.f};
        float* tileb = attn + ((size_t)bh * S_LEN + q0) * S_LEN + k0;
#pragma unroll
        for (int i = 0; i < 4; ++i) {
            int c = tid + i * 256;       // 64 rows x 16 float4
            int row = c >> 4, c4 = c & 15;
            *(float4*)&tileb[(size_t)row * S_LEN + c4 * 4] = z;
        }
        return;
    }

    const int w = tid >> 6, l = tid & 63, lm = l & 15, quad = l >> 4;
    __shared__ __align__(16) short Qs[64][72];
    __shared__ __align__(16) short Ks[64][72];
    __shared__ float padf[64];

#pragma unroll
    for (int i = 0; i < 2; ++i) {
        int idx = tid + i * 256;
        int r = idx >> 3, c8 = idx & 7;
        *(int4*)&Qs[r][c8 * 8] =
            *(const int4*)&QKV[((size_t)(b * S_LEN + q0 + r)) * QKVN + h * DK + c8 * 8];
        *(int4*)&Ks[r][c8 * 8] =
            *(const int4*)&QKV[((size_t)(b * S_LEN + k0 + r)) * QKVN + 1024 + h * DK + c8 * 8];
    }
    if (tid < 64) padf[tid] = (tok[b * S_LEN + k0 + tid] == 0) ? 1.f : 0.f;
    __syncthreads();

    float rp[4] = {0.f, 0.f, 0.f, 0.f};
#pragma unroll
    for (int nt = 0; nt < 4; ++nt) {
        f32x4 acc = {0.f, 0.f, 0.f, 0.f};
#pragma unroll
        for (int kc = 0; kc < 2; ++kc) {
            bf16x8 a = *(const bf16x8*)&Qs[w * 16 + lm][kc * 32 + quad * 8];
            bf16x8 bb = *(const bf16x8*)&Ks[nt * 16 + lm][kc * 32 + quad * 8];
            acc = mfma16(a, bb, acc);
        }
        int kcol = k0 + nt * 16 + lm;
        bool pad = padf[nt * 16 + lm] != 0.f;
#pragma unroll
        for (int r = 0; r < 4; ++r) {
            int qrow = q0 + w * 16 + quad * 4 + r;
            bool msk = pad || (kcol > qrow);
            rp[r] += msk ? 0.f : __expf(acc[r] * 0.125f - SM_SHIFT);
        }
    }
#pragma unroll
    for (int off = 1; off < 16; off <<= 1)
#pragma unroll
        for (int r = 0; r < 4; ++r) rp[r] += __shfl_xor(rp[r], off);

    if (lm == 0) {
#pragma unroll
        for (int r = 0; r < 4; ++r)
            atomicAdd(&Lrow[(size_t)bh * S_LEN + q0 + w * 16 + quad * 4 + r], rp[r]);
    }
}

// ---------------------------------------------------------------------------
// Pass B: p = exp(s-8)/l, write fp32 attn (causal band, normalized, once),
// P -> LDS bf16 -> MFMA P@V -> ctx bf16.
// ---------------------------------------------------------------------------
__global__ __launch_bounds__(256) void flash_pb(
    const short* __restrict__ QKV, const short* __restrict__ Vt,
    const int* __restrict__ tok, const float* __restrict__ Lrow,
    float* __restrict__ attn, short* __restrict__ ctxb) {
    const int bh = blockIdx.y, b = bh >> 4, h = bh & 15;
    const int qt = blockIdx.x, q0 = qt * 64;
    const int tid = threadIdx.x;
    const int w = tid >> 6, l = tid & 63, lm = l & 15, quad = l >> 4;
    __shared__ __align__(16) short Qs[64][72];
    __shared__ __align__(16) short Ks[64][72];
    __shared__ __align__(16) short Vs[64][72];
    __shared__ __align__(16) short Ps[64][72];
    __shared__ float padf[64];

#pragma unroll
    for (int i = 0; i < 2; ++i) {
        int idx = tid + i * 256;
        int r = idx >> 3, c8 = idx & 7;
        *(int4*)&Qs[r][c8 * 8] =
            *(const int4*)&QKV[((size_t)(b * S_LEN + q0 + r)) * QKVN + h * DK + c8 * 8];
    }

    float linv[4];
#pragma unroll
    for (int r = 0; r < 4; ++r)
        linv[r] = 1.f / Lrow[(size_t)bh * S_LEN + q0 + w * 16 + quad * 4 + r];

    f32x4 oacc[4] = {};

    for (int kt = 0; kt <= qt; ++kt) {
        __syncthreads();
#pragma unroll
        for (int i = 0; i < 2; ++i) {
            int idx = tid + i * 256;
            int r = idx >> 3, c8 = idx & 7;
            *(int4*)&Ks[r][c8 * 8] =
                *(const int4*)&QKV[((size_t)(b * S_LEN + kt * 64 + r)) * QKVN + 1024 + h * DK + c8 * 8];
            *(int4*)&Vs[r][c8 * 8] =
                *(const int4*)&Vt[((size_t)(bh * DK + r)) * S_LEN + kt * 64 + c8 * 8];
        }
        if (tid < 64) padf[tid] = (tok[b * S_LEN + kt * 64 + tid] == 0) ? 1.f : 0.f;
        __syncthreads();

#pragma unroll
        for (int nt = 0; nt < 4; ++nt) {
            f32x4 acc = {0.f, 0.f, 0.f, 0.f};
#pragma unroll
            for (int kc = 0; kc < 2; ++kc) {
                bf16x8 a = *(const bf16x8*)&Qs[w * 16 + lm][kc * 32 + quad * 8];
                bf16x8 bb = *(const bf16x8*)&Ks[nt * 16 + lm][kc * 32 + quad * 8];
                acc = mfma16(a, bb, acc);
            }
            int kcol = kt * 64 + nt * 16 + lm;
            bool pad = padf[nt * 16 + lm] != 0.f;
#pragma unroll
            for (int r = 0; r < 4; ++r) {
                int qrow = q0 + w * 16 + quad * 4 + r;
                bool msk = pad || (kcol > qrow);
                float p = msk ? 0.f : __expf(acc[r] * 0.125f - SM_SHIFT) * linv[r];
                attn[((size_t)bh * S_LEN + qrow) * S_LEN + kcol] = p;
                Ps[w * 16 + quad * 4 + r][nt * 16 + lm] = f2bf(p);
            }
        }
        // P (written by this wave's own lanes) -> A-frags; V -> B-frags
#pragma unroll
        for (int kc = 0; kc < 2; ++kc) {
            bf16x8 a = *(const bf16x8*)&Ps[w * 16 + lm][kc * 32 + quad * 8];
#pragma unroll
            for (int dt = 0; dt < 4; ++dt) {
                bf16x8 bv = *(const bf16x8*)&Vs[dt * 16 + lm][kc * 32 + quad * 8];
                oacc[dt] = mfma16(a, bv, oacc[dt]);
            }
        }
    }

#pragma unroll
    for (int dt = 0; dt < 4; ++dt)
#pragma unroll
        for (int r = 0; r < 4; ++r) {
            int qrow = q0 + w * 16 + quad * 4 + r;
            ctxb[((size_t)(b * S_LEN + qrow)) * DMODEL + h * DK + dt * 16 + lm] =
                f2bf(oacc[dt][r]);
        }
}

// ---------------------------------------------------------------------------
// Fully-masked rows (q < first-nonpad): attn row = 1/2048 (all heads),
// ctx row = mean(V). Rare/usually-empty; blocks early-out.
// ---------------------------------------------------------------------------
__global__ __launch_bounds__(256) void fix_fullmask(
    const int* __restrict__ fnp, const short* __restrict__ QKV,
    float* __restrict__ attn, short* __restrict__ ctxb) {
    const int b = blockIdx.x >> 11, q = blockIdx.x & 2047;
    if (q >= fnp[b]) return;
    const float u = 1.f / (float)S_LEN;
    float4 uu = {u, u, u, u};
    for (int i = threadIdx.x; i < NH * (S_LEN / 4); i += 256) {
        int h = i / (S_LEN / 4), c4 = i % (S_LEN / 4);
        *(float4*)&attn[(((size_t)(b * NH + h) * S_LEN + q)) * S_LEN + c4 * 4] = uu;
    }
    for (int d = threadIdx.x; d < DMODEL; d += 256) {
        float sv = 0.f;
        for (int s = 0; s < S_LEN; ++s)
            sv += bf2f(QKV[((size_t)(b * S_LEN + s)) * QKVN + 2048 + d]);
        ctxb[((size_t)(b * S_LEN + q)) * DMODEL + d] = f2bf(sv * u);
    }
}

extern "C" void kernel_launch(void* const* d_in, const int* in_sizes, int n_in,
                              void* d_out, int out_size, void* d_ws, size_t ws_size,
                              hipStream_t stream) {
    const float* x  = (const float*)d_in[0];
    const int*  tok = (const int*)d_in[1];
    const float* wq = (const float*)d_in[2];
    const float* bq = (const float*)d_in[3];
    const float* wk = (const float*)d_in[4];
    const float* bk = (const float*)d_in[5];
    const float* wv = (const float*)d_in[6];
    const float* bv = (const float*)d_in[7];
    const float* wo = (const float*)d_in[8];
    const float* bo = (const float*)d_in[9];

    float* out  = (float*)d_out;
    float* attn = out + (size_t)B_SZ * S_LEN * DMODEL;

    const size_t NTOK = (size_t)B_SZ * S_LEN;        // 4096
    const size_t NE   = NTOK * DMODEL;               // 4,194,304
    const size_t WSZ  = (size_t)DMODEL * DMODEL;     // 1M elements
    short* xb    = (short*)d_ws;                     // [4096][1024]
    short* Wt3   = xb + NE;                          // [3072][1024]
    short* Wto   = Wt3 + 3 * WSZ;                    // [1024][1024]
    short* QKVb  = Wto + WSZ;                        // [4096][3072]
    short* Vt    = QKVb + NTOK * QKVN;               // [32][64][2048]
    short* ctxb  = Vt + NE;                          // [4096][1024]
    float* cbias = (float*)(ctxb + NE);              // [3072]
    float* Lrow  = cbias + QKVN;                     // [32][2048]
    int*   fnp   = (int*)(Lrow + (size_t)B_SZ * NH * S_LEN);

    dim3 blk(256);

    cvt_bf16<<<dim3((int)(NE / 4 / 256)), blk, 0, stream>>>(x, xb, (int)(NE / 4));
    wtrans<<<dim3(16, 16), blk, 0, stream>>>(wq, Wt3 + 0 * WSZ);
    wtrans<<<dim3(16, 16), blk, 0, stream>>>(wk, Wt3 + 1 * WSZ);
    wtrans<<<dim3(16, 16), blk, 0, stream>>>(wv, Wt3 + 2 * WSZ);
    wtrans<<<dim3(16, 16), blk, 0, stream>>>(wo, Wto);
    cbias_cat<<<dim3(QKVN / 256), blk, 0, stream>>>(bq, bk, bv, cbias);
    lzero<<<dim3((int)(B_SZ * NH * S_LEN / 1024)), blk, 0, stream>>>(Lrow);

    gemm128<<<dim3(QKVN / 128, (int)(NTOK / 128)), blk, 0, stream>>>(
        xb, Wt3, cbias, QKVb, (int)NTOK, QKVN, DMODEL);

    vtrans<<<dim3(S_LEN / 64, B_SZ * NH), blk, 0, stream>>>(QKVb, Vt);
    fnp_scan<<<dim3(B_SZ), blk, 0, stream>>>(tok, fnp);

    lsum_par<<<dim3((S_LEN / 64) * (S_LEN / 64), B_SZ * NH), blk, 0, stream>>>(
        QKVb, tok, Lrow, attn);
    flash_pb<<<dim3(S_LEN / 64, B_SZ * NH), blk, 0, stream>>>(QKVb, Vt, tok, Lrow,
                                                              attn, ctxb);
    fix_fullmask<<<dim3(B_SZ * S_LEN), blk, 0, stream>>>(fnp, QKVb, attn, ctxb);

    gemm64<<<dim3(DMODEL / 64, (int)(NTOK / 64)), blk, 0, stream>>>(
        ctxb, Wto, bo, out, (int)NTOK, DMODEL, DMODEL);
}

// Round 5
// 817.556 us; speedup vs baseline: 1.1094x; 1.0133x over previous
//
#include <hip/hip_runtime.h>
#include <hip/hip_bf16.h>
#include <math.h>

#define S_LEN 2048
#define B_SZ 2
#define DMODEL 1024
#define NH 16
#define DK 64
#define QKVN 3072          // fused QKV output width
#define SM_SHIFT 8.0f      // constant softmax shift: exp(s-8); exact after /l

typedef __attribute__((ext_vector_type(8))) short bf16x8;
typedef __attribute__((ext_vector_type(4))) float f32x4;

__device__ inline short f2bf(float f) {
    __hip_bfloat16 h = __float2bfloat16(f);
    return __builtin_bit_cast(short, h);
}
__device__ inline float bf2f(short s) {
    unsigned int u = ((unsigned int)(unsigned short)s) << 16;
    return __builtin_bit_cast(float, u);
}
__device__ inline f32x4 mfma16(bf16x8 a, bf16x8 b, f32x4 c) {
    return __builtin_amdgcn_mfma_f32_16x16x32_bf16(a, b, c, 0, 0, 0);
}
// async global->LDS, 16B per lane; LDS dest = wave-uniform base + lane*16
__device__ inline void gl_lds16(const void* g, void* l) {
    __builtin_amdgcn_global_load_lds(
        (const __attribute__((address_space(1))) void*)g,
        (__attribute__((address_space(3))) void*)l, 16, 0, 0);
}

// ---------------------------------------------------------------------------
// Fused prep: one dispatch replacing cvt_bf16, 4x wtrans, cbias_cat, lzero,
// fnp_scan. Block ranges:
//   [0,4096)      : x fp32 -> bf16 (xb)
//   [4096,5120)   : 4 weight transposes (256 blocks each)
//   [5120,5132)   : cbias concat
//   [5132,5196)   : Lrow zero
//   [5196,5198)   : first-nonpad scan
// ---------------------------------------------------------------------------
#define PREP_CVT0 0
#define PREP_WT0  4096
#define PREP_CB0  5120
#define PREP_LZ0  5132
#define PREP_FNP0 5196
#define PREP_NBLK 5198

__global__ __launch_bounds__(256) void prep(
    const float* __restrict__ x,
    const float* __restrict__ wq, const float* __restrict__ wk,
    const float* __restrict__ wv, const float* __restrict__ wo,
    const float* __restrict__ bq, const float* __restrict__ bk,
    const float* __restrict__ bv, const int* __restrict__ tok,
    short* __restrict__ xb, short* __restrict__ Wt3, short* __restrict__ Wto,
    float* __restrict__ cbias, float* __restrict__ Lrow, int* __restrict__ fnp) {
    const int bid = blockIdx.x;
    const int tid = threadIdx.x;
    __shared__ __align__(16) short T[64][72];
    __shared__ int mn;

    if (bid < PREP_WT0) {                         // ---- x -> bf16
        int i = bid * 256 + tid;                  // i < 1,048,576
        float4 v = *(const float4*)&x[(size_t)i * 4];
        short4 o = { f2bf(v.x), f2bf(v.y), f2bf(v.z), f2bf(v.w) };
        *(short4*)&xb[(size_t)i * 4] = o;
    } else if (bid < PREP_CB0) {                  // ---- weight transpose
        int widx = (bid - PREP_WT0) >> 8;
        int sub  = (bid - PREP_WT0) & 255;
        int k0 = (sub & 15) * 64, n0 = (sub >> 4) * 64;
        const float* W = widx == 0 ? wq : (widx == 1 ? wk : (widx == 2 ? wv : wo));
        short* Wt = widx < 3 ? Wt3 + (size_t)widx * DMODEL * DMODEL : Wto;
#pragma unroll
        for (int i = 0; i < 4; ++i) {
            int idx = tid + i * 256;              // 64 k-rows x 16 float4
            int kr = idx >> 4, n4 = idx & 15;
            float4 v = *(const float4*)&W[(size_t)(k0 + kr) * DMODEL + n0 + n4 * 4];
            short4 o = { f2bf(v.x), f2bf(v.y), f2bf(v.z), f2bf(v.w) };
            *(short4*)&T[kr][n4 * 4] = o;
        }
        __syncthreads();
#pragma unroll
        for (int i = 0; i < 2; ++i) {
            int idx = tid + i * 256;              // 64 n-rows x 8 chunks
            int n = idx >> 3, c8 = idx & 7;
            short v[8];
#pragma unroll
            for (int j = 0; j < 8; ++j) v[j] = T[c8 * 8 + j][n];
            *(int4*)&Wt[(size_t)(n0 + n) * DMODEL + k0 + c8 * 8] = *(int4*)v;
        }
    } else if (bid < PREP_LZ0) {                  // ---- cbias concat
        int i = (bid - PREP_CB0) * 256 + tid;
        cbias[i] = i < 1024 ? bq[i] : (i < 2048 ? bk[i - 1024] : bv[i - 2048]);
    } else if (bid < PREP_FNP0) {                 // ---- Lrow zero
        float4 z = {0.f, 0.f, 0.f, 0.f};
        *(float4*)&Lrow[(size_t)((bid - PREP_LZ0) * 256 + tid) * 4] = z;
    } else {                                      // ---- first-nonpad scan
        int b = bid - PREP_FNP0;
        if (tid == 0) mn = S_LEN;
        __syncthreads();
        int loc = S_LEN;
        for (int s = tid; s < S_LEN; s += 256)
            if (tok[b * S_LEN + s] != 0) loc = min(loc, s);
        atomicMin(&mn, loc);
        __syncthreads();
        if (tid == 0) fnp[b] = mn;
    }
}

// ---------------------------------------------------------------------------
// 128x128-tile MFMA GEMM (m97 structure): C[M,N] = A[M,K] @ Bt[N,K]^T + bias.
// BK=64, global_load_lds width-16 staging. 4 waves (2x2), 64x64 per wave.
// ---------------------------------------------------------------------------
__global__ __launch_bounds__(256) void gemm128(
    const short* __restrict__ A, const short* __restrict__ Bt,
    const float* __restrict__ bias, short* __restrict__ C,
    int M, int N, int K) {
    __shared__ __align__(16) short As[128][64];   // linear: required by gl_lds16
    __shared__ __align__(16) short Bs[128][64];
    const int row0 = blockIdx.y * 128, col0 = blockIdx.x * 128;
    const int tid = threadIdx.x;
    const int w = tid >> 6, l = tid & 63, lm = l & 15, quad = l >> 4;
    const int wm = (w >> 1) * 64, wn = (w & 1) * 64;
    const int lrow = tid >> 3, lc8 = tid & 7;     // 32 rows x 8 chunks per issue
    f32x4 acc[4][4] = {};

    for (int k0 = 0; k0 < K; k0 += 64) {
        __syncthreads();
#pragma unroll
        for (int i = 0; i < 4; ++i)               // A: 128 rows, 32/issue
            gl_lds16(&A[(size_t)(row0 + i * 32 + lrow) * K + k0 + lc8 * 8],
                     (short*)As + (i * 32 + w * 8) * 64);
#pragma unroll
        for (int i = 0; i < 4; ++i)               // B: 128 rows
            gl_lds16(&Bt[(size_t)(col0 + i * 32 + lrow) * K + k0 + lc8 * 8],
                     (short*)Bs + (i * 32 + w * 8) * 64);
        __syncthreads();                          // drains vmcnt before barrier
#pragma unroll
        for (int kc = 0; kc < 2; ++kc) {
            bf16x8 a[4], b[4];
#pragma unroll
            for (int mi = 0; mi < 4; ++mi)
                a[mi] = *(const bf16x8*)&As[wm + mi * 16 + lm][kc * 32 + quad * 8];
#pragma unroll
            for (int ni = 0; ni < 4; ++ni)
                b[ni] = *(const bf16x8*)&Bs[wn + ni * 16 + lm][kc * 32 + quad * 8];
#pragma unroll
            for (int mi = 0; mi < 4; ++mi)
#pragma unroll
                for (int ni = 0; ni < 4; ++ni)
                    acc[mi][ni] = mfma16(a[mi], b[ni], acc[mi][ni]);
        }
    }
#pragma unroll
    for (int mi = 0; mi < 4; ++mi)
#pragma unroll
        for (int ni = 0; ni < 4; ++ni) {
            int col = col0 + wn + ni * 16 + lm;
            float bs = bias[col];
#pragma unroll
            for (int r = 0; r < 4; ++r) {
                int row = row0 + wm + mi * 16 + quad * 4 + r;
                C[(size_t)row * N + col] = f2bf(acc[mi][ni][r] + bs);
            }
        }
}

// ---------------------------------------------------------------------------
// 64x64-tile bf16 MFMA GEMM, fp32 out (output projection; 4 blocks/CU).
// ---------------------------------------------------------------------------
__global__ __launch_bounds__(256) void gemm64(
    const short* __restrict__ A, const short* __restrict__ Bt,
    const float* __restrict__ bias, float* __restrict__ Cout,
    int M, int N, int K) {
    __shared__ __align__(16) short As[64][72];
    __shared__ __align__(16) short Bs[64][72];
    const int row0 = blockIdx.y * 64, col0 = blockIdx.x * 64;
    const int tid = threadIdx.x;
    const int w = tid >> 6, l = tid & 63, lm = l & 15, quad = l >> 4;
    const int wm = (w >> 1) * 32, wn = (w & 1) * 32;
    f32x4 acc[2][2] = {};

    for (int k0 = 0; k0 < K; k0 += 64) {
        __syncthreads();
#pragma unroll
        for (int i = 0; i < 2; ++i) {
            int idx = tid + i * 256;
            int r = idx >> 3, c8 = idx & 7;
            *(int4*)&As[r][c8 * 8] = *(const int4*)&A[(size_t)(row0 + r) * K + k0 + c8 * 8];
            *(int4*)&Bs[r][c8 * 8] = *(const int4*)&Bt[(size_t)(col0 + r) * K + k0 + c8 * 8];
        }
        __syncthreads();
#pragma unroll
        for (int kc = 0; kc < 2; ++kc) {
            bf16x8 a0 = *(const bf16x8*)&As[wm + lm][kc * 32 + quad * 8];
            bf16x8 a1 = *(const bf16x8*)&As[wm + 16 + lm][kc * 32 + quad * 8];
            bf16x8 b0 = *(const bf16x8*)&Bs[wn + lm][kc * 32 + quad * 8];
            bf16x8 b1 = *(const bf16x8*)&Bs[wn + 16 + lm][kc * 32 + quad * 8];
            acc[0][0] = mfma16(a0, b0, acc[0][0]);
            acc[0][1] = mfma16(a0, b1, acc[0][1]);
            acc[1][0] = mfma16(a1, b0, acc[1][0]);
            acc[1][1] = mfma16(a1, b1, acc[1][1]);
        }
    }
#pragma unroll
    for (int mi = 0; mi < 2; ++mi)
#pragma unroll
        for (int ni = 0; ni < 2; ++ni)
#pragma unroll
            for (int r = 0; r < 4; ++r) {
                int row = row0 + wm + mi * 16 + quad * 4 + r;
                int col = col0 + wn + ni * 16 + lm;
                Cout[(size_t)row * N + col] = acc[mi][ni][r] + bias[col];
            }
}

// ---------------------------------------------------------------------------
// V transpose (per head): QKV bf16 [b][s][3072] (V at col 2048) ->
// Vt bf16 [bh][64 d][2048 s]
// ---------------------------------------------------------------------------
__global__ __launch_bounds__(256) void vtrans(const short* __restrict__ QKV,
                                              short* __restrict__ Vt) {
    __shared__ __align__(16) short T[64][72];
    const int bh = blockIdx.y, b = bh >> 4, h = bh & 15;
    const int s0 = blockIdx.x * 64;
    const int tid = threadIdx.x;
#pragma unroll
    for (int i = 0; i < 2; ++i) {
        int idx = tid + i * 256;          // 64 token-rows x 8 chunks
        int r = idx >> 3, c8 = idx & 7;
        *(int4*)&T[r][c8 * 8] =
            *(const int4*)&QKV[((size_t)(b * S_LEN + s0 + r)) * QKVN + 2048 + h * DK + c8 * 8];
    }
    __syncthreads();
#pragma unroll
    for (int i = 0; i < 2; ++i) {
        int idx = tid + i * 256;          // 64 d-rows x 8 chunks
        int d = idx >> 3, c8 = idx & 7;
        short v[8];
#pragma unroll
        for (int j = 0; j < 8; ++j) v[j] = T[c8 * 8 + j][d];
        *(int4*)&Vt[((size_t)(bh * DK + d)) * S_LEN + s0 + c8 * 8] = *(int4*)v;
    }
}

// ---------------------------------------------------------------------------
// Parallel l-sum: grid (qt*32+kt, bh). Band tiles: QK^T via MFMA,
// p = exp(s-8), intra-tile row-sum (4-step shuffle over the 16 lm lanes),
// atomicAdd into Lrow. Strict-upper tiles: write attn zeros instead
// (absorbs fill_upper into otherwise-idle blocks).
// ---------------------------------------------------------------------------
__global__ __launch_bounds__(256) void lsum_par(
    const short* __restrict__ QKV, const int* __restrict__ tok,
    float* __restrict__ Lrow, float* __restrict__ attn) {
    const int bh = blockIdx.y, b = bh >> 4, h = bh & 15;
    const int qt = blockIdx.x >> 5, kt = blockIdx.x & 31;
    const int q0 = qt * 64, k0 = kt * 64;
    const int tid = threadIdx.x;

    if (kt > qt) {                       // causal-masked tile: zeros only
        float4 z = {0.f, 0.f, 0.f, 0.f};
        float* tileb = attn + ((size_t)bh * S_LEN + q0) * S_LEN + k0;
#pragma unroll
        for (int i = 0; i < 4; ++i) {
            int c = tid + i * 256;       // 64 rows x 16 float4
            int row = c >> 4, c4 = c & 15;
            *(float4*)&tileb[(size_t)row * S_LEN + c4 * 4] = z;
        }
        return;
    }

    const int w = tid >> 6, l = tid & 63, lm = l & 15, quad = l >> 4;
    __shared__ __align__(16) short Qs[64][72];
    __shared__ __align__(16) short Ks[64][72];
    __shared__ float padf[64];

#pragma unroll
    for (int i = 0; i < 2; ++i) {
        int idx = tid + i * 256;
        int r = idx >> 3, c8 = idx & 7;
        *(int4*)&Qs[r][c8 * 8] =
            *(const int4*)&QKV[((size_t)(b * S_LEN + q0 + r)) * QKVN + h * DK + c8 * 8];
        *(int4*)&Ks[r][c8 * 8] =
            *(const int4*)&QKV[((size_t)(b * S_LEN + k0 + r)) * QKVN + 1024 + h * DK + c8 * 8];
    }
    if (tid < 64) padf[tid] = (tok[b * S_LEN + k0 + tid] == 0) ? 1.f : 0.f;
    __syncthreads();

    float rp[4] = {0.f, 0.f, 0.f, 0.f};
#pragma unroll
    for (int nt = 0; nt < 4; ++nt) {
        f32x4 acc = {0.f, 0.f, 0.f, 0.f};
#pragma unroll
        for (int kc = 0; kc < 2; ++kc) {
            bf16x8 a = *(const bf16x8*)&Qs[w * 16 + lm][kc * 32 + quad * 8];
            bf16x8 bb = *(const bf16x8*)&Ks[nt * 16 + lm][kc * 32 + quad * 8];
            acc = mfma16(a, bb, acc);
        }
        int kcol = k0 + nt * 16 + lm;
        bool pad = padf[nt * 16 + lm] != 0.f;
#pragma unroll
        for (int r = 0; r < 4; ++r) {
            int qrow = q0 + w * 16 + quad * 4 + r;
            bool msk = pad || (kcol > qrow);
            rp[r] += msk ? 0.f : __expf(acc[r] * 0.125f - SM_SHIFT);
        }
    }
#pragma unroll
    for (int off = 1; off < 16; off <<= 1)
#pragma unroll
        for (int r = 0; r < 4; ++r) rp[r] += __shfl_xor(rp[r], off);

    if (lm == 0) {
#pragma unroll
        for (int r = 0; r < 4; ++r)
            atomicAdd(&Lrow[(size_t)bh * S_LEN + q0 + w * 16 + quad * 4 + r], rp[r]);
    }
}

// ---------------------------------------------------------------------------
// Pass B: p = exp(s-8)/l, write fp32 attn (causal band, normalized, once),
// P -> LDS bf16 -> MFMA P@V -> ctx bf16.
// ---------------------------------------------------------------------------
__global__ __launch_bounds__(256) void flash_pb(
    const short* __restrict__ QKV, const short* __restrict__ Vt,
    const int* __restrict__ tok, const float* __restrict__ Lrow,
    float* __restrict__ attn, short* __restrict__ ctxb) {
    const int bh = blockIdx.y, b = bh >> 4, h = bh & 15;
    const int qt = blockIdx.x, q0 = qt * 64;
    const int tid = threadIdx.x;
    const int w = tid >> 6, l = tid & 63, lm = l & 15, quad = l >> 4;
    __shared__ __align__(16) short Qs[64][72];
    __shared__ __align__(16) short Ks[64][72];
    __shared__ __align__(16) short Vs[64][72];
    __shared__ __align__(16) short Ps[64][72];
    __shared__ float padf[64];

#pragma unroll
    for (int i = 0; i < 2; ++i) {
        int idx = tid + i * 256;
        int r = idx >> 3, c8 = idx & 7;
        *(int4*)&Qs[r][c8 * 8] =
            *(const int4*)&QKV[((size_t)(b * S_LEN + q0 + r)) * QKVN + h * DK + c8 * 8];
    }

    float linv[4];
#pragma unroll
    for (int r = 0; r < 4; ++r)
        linv[r] = 1.f / Lrow[(size_t)bh * S_LEN + q0 + w * 16 + quad * 4 + r];

    f32x4 oacc[4] = {};

    for (int kt = 0; kt <= qt; ++kt) {
        __syncthreads();
#pragma unroll
        for (int i = 0; i < 2; ++i) {
            int idx = tid + i * 256;
            int r = idx >> 3, c8 = idx & 7;
            *(int4*)&Ks[r][c8 * 8] =
                *(const int4*)&QKV[((size_t)(b * S_LEN + kt * 64 + r)) * QKVN + 1024 + h * DK + c8 * 8];
            *(int4*)&Vs[r][c8 * 8] =
                *(const int4*)&Vt[((size_t)(bh * DK + r)) * S_LEN + kt * 64 + c8 * 8];
        }
        if (tid < 64) padf[tid] = (tok[b * S_LEN + kt * 64 + tid] == 0) ? 1.f : 0.f;
        __syncthreads();

#pragma unroll
        for (int nt = 0; nt < 4; ++nt) {
            f32x4 acc = {0.f, 0.f, 0.f, 0.f};
#pragma unroll
            for (int kc = 0; kc < 2; ++kc) {
                bf16x8 a = *(const bf16x8*)&Qs[w * 16 + lm][kc * 32 + quad * 8];
                bf16x8 bb = *(const bf16x8*)&Ks[nt * 16 + lm][kc * 32 + quad * 8];
                acc = mfma16(a, bb, acc);
            }
            int kcol = kt * 64 + nt * 16 + lm;
            bool pad = padf[nt * 16 + lm] != 0.f;
#pragma unroll
            for (int r = 0; r < 4; ++r) {
                int qrow = q0 + w * 16 + quad * 4 + r;
                bool msk = pad || (kcol > qrow);
                float p = msk ? 0.f : __expf(acc[r] * 0.125f - SM_SHIFT) * linv[r];
                attn[((size_t)bh * S_LEN + qrow) * S_LEN + kcol] = p;
                Ps[w * 16 + quad * 4 + r][nt * 16 + lm] = f2bf(p);
            }
        }
        // P (written by this wave's own lanes) -> A-frags; V -> B-frags
#pragma unroll
        for (int kc = 0; kc < 2; ++kc) {
            bf16x8 a = *(const bf16x8*)&Ps[w * 16 + lm][kc * 32 + quad * 8];
#pragma unroll
            for (int dt = 0; dt < 4; ++dt) {
                bf16x8 bv = *(const bf16x8*)&Vs[dt * 16 + lm][kc * 32 + quad * 8];
                oacc[dt] = mfma16(a, bv, oacc[dt]);
            }
        }
    }

#pragma unroll
    for (int dt = 0; dt < 4; ++dt)
#pragma unroll
        for (int r = 0; r < 4; ++r) {
            int qrow = q0 + w * 16 + quad * 4 + r;
            ctxb[((size_t)(b * S_LEN + qrow)) * DMODEL + h * DK + dt * 16 + lm] =
                f2bf(oacc[dt][r]);
        }
}

// ---------------------------------------------------------------------------
// Fully-masked rows (q < first-nonpad): attn row = 1/2048 (all heads),
// ctx row = mean(V). Rare/usually-empty; blocks early-out.
// ---------------------------------------------------------------------------
__global__ __launch_bounds__(256) void fix_fullmask(
    const int* __restrict__ fnp, const short* __restrict__ QKV,
    float* __restrict__ attn, short* __restrict__ ctxb) {
    const int b = blockIdx.x >> 11, q = blockIdx.x & 2047;
    if (q >= fnp[b]) return;
    const float u = 1.f / (float)S_LEN;
    float4 uu = {u, u, u, u};
    for (int i = threadIdx.x; i < NH * (S_LEN / 4); i += 256) {
        int h = i / (S_LEN / 4), c4 = i % (S_LEN / 4);
        *(float4*)&attn[(((size_t)(b * NH + h) * S_LEN + q)) * S_LEN + c4 * 4] = uu;
    }
    for (int d = threadIdx.x; d < DMODEL; d += 256) {
        float sv = 0.f;
        for (int s = 0; s < S_LEN; ++s)
            sv += bf2f(QKV[((size_t)(b * S_LEN + s)) * QKVN + 2048 + d]);
        ctxb[((size_t)(b * S_LEN + q)) * DMODEL + d] = f2bf(sv * u);
    }
}

extern "C" void kernel_launch(void* const* d_in, const int* in_sizes, int n_in,
                              void* d_out, int out_size, void* d_ws, size_t ws_size,
                              hipStream_t stream) {
    const float* x  = (const float*)d_in[0];
    const int*  tok = (const int*)d_in[1];
    const float* wq = (const float*)d_in[2];
    const float* bq = (const float*)d_in[3];
    const float* wk = (const float*)d_in[4];
    const float* bk = (const float*)d_in[5];
    const float* wv = (const float*)d_in[6];
    const float* bv = (const float*)d_in[7];
    const float* wo = (const float*)d_in[8];
    const float* bo = (const float*)d_in[9];

    float* out  = (float*)d_out;
    float* attn = out + (size_t)B_SZ * S_LEN * DMODEL;

    const size_t NTOK = (size_t)B_SZ * S_LEN;        // 4096
    const size_t NE   = NTOK * DMODEL;               // 4,194,304
    const size_t WSZ  = (size_t)DMODEL * DMODEL;     // 1M elements
    short* xb    = (short*)d_ws;                     // [4096][1024]
    short* Wt3   = xb + NE;                          // [3072][1024]
    short* Wto   = Wt3 + 3 * WSZ;                    // [1024][1024]
    short* QKVb  = Wto + WSZ;                        // [4096][3072]
    short* Vt    = QKVb + NTOK * QKVN;               // [32][64][2048]
    short* ctxb  = Vt + NE;                          // [4096][1024]
    float* cbias = (float*)(ctxb + NE);              // [3072]
    float* Lrow  = cbias + QKVN;                     // [32][2048]
    int*   fnp   = (int*)(Lrow + (size_t)B_SZ * NH * S_LEN);

    dim3 blk(256);

    prep<<<dim3(PREP_NBLK), blk, 0, stream>>>(x, wq, wk, wv, wo, bq, bk, bv, tok,
                                              xb, Wt3, Wto, cbias, Lrow, fnp);

    gemm128<<<dim3(QKVN / 128, (int)(NTOK / 128)), blk, 0, stream>>>(
        xb, Wt3, cbias, QKVb, (int)NTOK, QKVN, DMODEL);

    vtrans<<<dim3(S_LEN / 64, B_SZ * NH), blk, 0, stream>>>(QKVb, Vt);

    lsum_par<<<dim3((S_LEN / 64) * (S_LEN / 64), B_SZ * NH), blk, 0, stream>>>(
        QKVb, tok, Lrow, attn);
    flash_pb<<<dim3(S_LEN / 64, B_SZ * NH), blk, 0, stream>>>(QKVb, Vt, tok, Lrow,
                                                              attn, ctxb);
    fix_fullmask<<<dim3(B_SZ * S_LEN), blk, 0, stream>>>(fnp, QKVb, attn, ctxb);

    gemm64<<<dim3(DMODEL / 64, (int)(NTOK / 64)), blk, 0, stream>>>(
        ctxb, Wto, bo, out, (int)NTOK, DMODEL, DMODEL);
}

// Round 8
// 812.422 us; speedup vs baseline: 1.1164x; 1.0063x over previous
//
#include <hip/hip_runtime.h>
#include <hip/hip_bf16.h>
#include <math.h>

#define S_LEN 2048
#define B_SZ 2
#define DMODEL 1024
#define NH 16
#define DK 64
#define QKVN 3072          // fused QKV output width
#define SM_SHIFT 8.0f      // constant softmax shift: exp(s-8); exact after /l

typedef __attribute__((ext_vector_type(8))) short bf16x8;
typedef __attribute__((ext_vector_type(4))) float f32x4;

__device__ inline short f2bf(float f) {
    __hip_bfloat16 h = __float2bfloat16(f);
    return __builtin_bit_cast(short, h);
}
__device__ inline float bf2f(short s) {
    unsigned int u = ((unsigned int)(unsigned short)s) << 16;
    return __builtin_bit_cast(float, u);
}
__device__ inline f32x4 mfma16(bf16x8 a, bf16x8 b, f32x4 c) {
    return __builtin_amdgcn_mfma_f32_16x16x32_bf16(a, b, c, 0, 0, 0);
}
// async global->LDS, 16B per lane; LDS dest = wave-uniform base + lane*16
__device__ inline void gl_lds16(const void* g, void* l) {
    __builtin_amdgcn_global_load_lds(
        (const __attribute__((address_space(1))) void*)g,
        (__attribute__((address_space(3))) void*)l, 16, 0, 0);
}

// ---------------------------------------------------------------------------
// Fused prep: one dispatch replacing cvt_bf16, 4x wtrans, cbias_cat, lzero,
// fnp_scan. Block ranges as in R5.
// ---------------------------------------------------------------------------
#define PREP_WT0  4096
#define PREP_CB0  5120
#define PREP_LZ0  5132
#define PREP_FNP0 5196
#define PREP_NBLK 5198

__global__ __launch_bounds__(256) void prep(
    const float* __restrict__ x,
    const float* __restrict__ wq, const float* __restrict__ wk,
    const float* __restrict__ wv, const float* __restrict__ wo,
    const float* __restrict__ bq, const float* __restrict__ bk,
    const float* __restrict__ bv, const int* __restrict__ tok,
    short* __restrict__ xb, short* __restrict__ Wt3, short* __restrict__ Wto,
    float* __restrict__ cbias, float* __restrict__ Lrow, int* __restrict__ fnp) {
    const int bid = blockIdx.x;
    const int tid = threadIdx.x;
    __shared__ __align__(16) short T[64][72];
    __shared__ int mn;

    if (bid < PREP_WT0) {                         // ---- x -> bf16
        int i = bid * 256 + tid;
        float4 v = *(const float4*)&x[(size_t)i * 4];
        short4 o = { f2bf(v.x), f2bf(v.y), f2bf(v.z), f2bf(v.w) };
        *(short4*)&xb[(size_t)i * 4] = o;
    } else if (bid < PREP_CB0) {                  // ---- weight transpose
        int widx = (bid - PREP_WT0) >> 8;
        int sub  = (bid - PREP_WT0) & 255;
        int k0 = (sub & 15) * 64, n0 = (sub >> 4) * 64;
        const float* W = widx == 0 ? wq : (widx == 1 ? wk : (widx == 2 ? wv : wo));
        short* Wt = widx < 3 ? Wt3 + (size_t)widx * DMODEL * DMODEL : Wto;
#pragma unroll
        for (int i = 0; i < 4; ++i) {
            int idx = tid + i * 256;
            int kr = idx >> 4, n4 = idx & 15;
            float4 v = *(const float4*)&W[(size_t)(k0 + kr) * DMODEL + n0 + n4 * 4];
            short4 o = { f2bf(v.x), f2bf(v.y), f2bf(v.z), f2bf(v.w) };
            *(short4*)&T[kr][n4 * 4] = o;
        }
        __syncthreads();
#pragma unroll
        for (int i = 0; i < 2; ++i) {
            int idx = tid + i * 256;
            int n = idx >> 3, c8 = idx & 7;
            short v[8];
#pragma unroll
            for (int j = 0; j < 8; ++j) v[j] = T[c8 * 8 + j][n];
            *(int4*)&Wt[(size_t)(n0 + n) * DMODEL + k0 + c8 * 8] = *(int4*)v;
        }
    } else if (bid < PREP_LZ0) {                  // ---- cbias concat
        int i = (bid - PREP_CB0) * 256 + tid;
        cbias[i] = i < 1024 ? bq[i] : (i < 2048 ? bk[i - 1024] : bv[i - 2048]);
    } else if (bid < PREP_FNP0) {                 // ---- Lrow zero
        float4 z = {0.f, 0.f, 0.f, 0.f};
        *(float4*)&Lrow[(size_t)((bid - PREP_LZ0) * 256 + tid) * 4] = z;
    } else {                                      // ---- first-nonpad scan
        int b = bid - PREP_FNP0;
        if (tid == 0) mn = S_LEN;
        __syncthreads();
        int loc = S_LEN;
        for (int s = tid; s < S_LEN; s += 256)
            if (tok[b * S_LEN + s] != 0) loc = min(loc, s);
        atomicMin(&mn, loc);
        __syncthreads();
        if (tid == 0) fnp[b] = mn;
    }
}

// ---------------------------------------------------------------------------
// 128x128-tile MFMA GEMM (m97 structure): C[M,N] = A[M,K] @ Bt[N,K]^T + bias.
// BK=64, global_load_lds width-16 staging. 4 waves (2x2), 64x64 per wave.
// bf16 output (QKV projection).
// ---------------------------------------------------------------------------
__global__ __launch_bounds__(256) void gemm128(
    const short* __restrict__ A, const short* __restrict__ Bt,
    const float* __restrict__ bias, short* __restrict__ C,
    int M, int N, int K) {
    __shared__ __align__(16) short As[128][64];   // linear: required by gl_lds16
    __shared__ __align__(16) short Bs[128][64];
    const int row0 = blockIdx.y * 128, col0 = blockIdx.x * 128;
    const int tid = threadIdx.x;
    const int w = tid >> 6, l = tid & 63, lm = l & 15, quad = l >> 4;
    const int wm = (w >> 1) * 64, wn = (w & 1) * 64;
    const int lrow = tid >> 3, lc8 = tid & 7;     // 32 rows x 8 chunks per issue
    f32x4 acc[4][4] = {};

    for (int k0 = 0; k0 < K; k0 += 64) {
        __syncthreads();
#pragma unroll
        for (int i = 0; i < 4; ++i)               // A: 128 rows, 32/issue
            gl_lds16(&A[(size_t)(row0 + i * 32 + lrow) * K + k0 + lc8 * 8],
                     (short*)As + (i * 32 + w * 8) * 64);
#pragma unroll
        for (int i = 0; i < 4; ++i)               // B: 128 rows
            gl_lds16(&Bt[(size_t)(col0 + i * 32 + lrow) * K + k0 + lc8 * 8],
                     (short*)Bs + (i * 32 + w * 8) * 64);
        __syncthreads();                          // drains vmcnt before barrier
#pragma unroll
        for (int kc = 0; kc < 2; ++kc) {
            bf16x8 a[4], b[4];
#pragma unroll
            for (int mi = 0; mi < 4; ++mi)
                a[mi] = *(const bf16x8*)&As[wm + mi * 16 + lm][kc * 32 + quad * 8];
#pragma unroll
            for (int ni = 0; ni < 4; ++ni)
                b[ni] = *(const bf16x8*)&Bs[wn + ni * 16 + lm][kc * 32 + quad * 8];
#pragma unroll
            for (int mi = 0; mi < 4; ++mi)
#pragma unroll
                for (int ni = 0; ni < 4; ++ni)
                    acc[mi][ni] = mfma16(a[mi], b[ni], acc[mi][ni]);
        }
    }
#pragma unroll
    for (int mi = 0; mi < 4; ++mi)
#pragma unroll
        for (int ni = 0; ni < 4; ++ni) {
            int col = col0 + wn + ni * 16 + lm;
            float bs = bias[col];
#pragma unroll
            for (int r = 0; r < 4; ++r) {
                int row = row0 + wm + mi * 16 + quad * 4 + r;
                C[(size_t)row * N + col] = f2bf(acc[mi][ni][r] + bs);
            }
        }
}

// ---------------------------------------------------------------------------
// Same verified body, fp32 output (output projection). A = bf16 ctxb.
// ---------------------------------------------------------------------------
__global__ __launch_bounds__(256) void gemm_out128f(
    const short* __restrict__ A, const short* __restrict__ Bt,
    const float* __restrict__ bias, float* __restrict__ Cout,
    int M, int N, int K) {
    __shared__ __align__(16) short As[128][64];
    __shared__ __align__(16) short Bs[128][64];
    const int row0 = blockIdx.y * 128, col0 = blockIdx.x * 128;
    const int tid = threadIdx.x;
    const int w = tid >> 6, l = tid & 63, lm = l & 15, quad = l >> 4;
    const int wm = (w >> 1) * 64, wn = (w & 1) * 64;
    const int lrow = tid >> 3, lc8 = tid & 7;
    f32x4 acc[4][4] = {};

    for (int k0 = 0; k0 < K; k0 += 64) {
        __syncthreads();
#pragma unroll
        for (int i = 0; i < 4; ++i)
            gl_lds16(&A[(size_t)(row0 + i * 32 + lrow) * K + k0 + lc8 * 8],
                     (short*)As + (i * 32 + w * 8) * 64);
#pragma unroll
        for (int i = 0; i < 4; ++i)
            gl_lds16(&Bt[(size_t)(col0 + i * 32 + lrow) * K + k0 + lc8 * 8],
                     (short*)Bs + (i * 32 + w * 8) * 64);
        __syncthreads();
#pragma unroll
        for (int kc = 0; kc < 2; ++kc) {
            bf16x8 a[4], b[4];
#pragma unroll
            for (int mi = 0; mi < 4; ++mi)
                a[mi] = *(const bf16x8*)&As[wm + mi * 16 + lm][kc * 32 + quad * 8];
#pragma unroll
            for (int ni = 0; ni < 4; ++ni)
                b[ni] = *(const bf16x8*)&Bs[wn + ni * 16 + lm][kc * 32 + quad * 8];
#pragma unroll
            for (int mi = 0; mi < 4; ++mi)
#pragma unroll
                for (int ni = 0; ni < 4; ++ni)
                    acc[mi][ni] = mfma16(a[mi], b[ni], acc[mi][ni]);
        }
    }
#pragma unroll
    for (int mi = 0; mi < 4; ++mi)
#pragma unroll
        for (int ni = 0; ni < 4; ++ni) {
            int col = col0 + wn + ni * 16 + lm;
            float bs = bias[col];
#pragma unroll
            for (int r = 0; r < 4; ++r) {
                int row = row0 + wm + mi * 16 + quad * 4 + r;
                Cout[(size_t)row * N + col] = acc[mi][ni][r] + bs;
            }
        }
}

// ---------------------------------------------------------------------------
// V transpose (per head): QKV bf16 [b][s][3072] (V at col 2048) ->
// Vt bf16 [bh][64 d][2048 s]
// ---------------------------------------------------------------------------
__global__ __launch_bounds__(256) void vtrans(const short* __restrict__ QKV,
                                              short* __restrict__ Vt) {
    __shared__ __align__(16) short T[64][72];
    const int bh = blockIdx.y, b = bh >> 4, h = bh & 15;
    const int s0 = blockIdx.x * 64;
    const int tid = threadIdx.x;
#pragma unroll
    for (int i = 0; i < 2; ++i) {
        int idx = tid + i * 256;
        int r = idx >> 3, c8 = idx & 7;
        *(int4*)&T[r][c8 * 8] =
            *(const int4*)&QKV[((size_t)(b * S_LEN + s0 + r)) * QKVN + 2048 + h * DK + c8 * 8];
    }
    __syncthreads();
#pragma unroll
    for (int i = 0; i < 2; ++i) {
        int idx = tid + i * 256;
        int d = idx >> 3, c8 = idx & 7;
        short v[8];
#pragma unroll
        for (int j = 0; j < 8; ++j) v[j] = T[c8 * 8 + j][d];
        *(int4*)&Vt[((size_t)(bh * DK + d)) * S_LEN + s0 + c8 * 8] = *(int4*)v;
    }
}

// ---------------------------------------------------------------------------
// Parallel l-sum: grid (qt*32+kt, bh). Band tiles: QK^T via MFMA,
// p = exp(s-8), intra-tile row-sum, atomicAdd into Lrow. Strict-upper
// tiles: write attn zeros instead (absorbs fill_upper).
// ---------------------------------------------------------------------------
__global__ __launch_bounds__(256) void lsum_par(
    const short* __restrict__ QKV, const int* __restrict__ tok,
    float* __restrict__ Lrow, float* __restrict__ attn) {
    const int bh = blockIdx.y, b = bh >> 4, h = bh & 15;
    const int qt = blockIdx.x >> 5, kt = blockIdx.x & 31;
    const int q0 = qt * 64, k0 = kt * 64;
    const int tid = threadIdx.x;

    if (kt > qt) {                       // causal-masked tile: zeros only
        float4 z = {0.f, 0.f, 0.f, 0.f};
        float* tileb = attn + ((size_t)bh * S_LEN + q0) * S_LEN + k0;
#pragma unroll
        for (int i = 0; i < 4; ++i) {
            int c = tid + i * 256;
            int row = c >> 4, c4 = c & 15;
            *(float4*)&tileb[(size_t)row * S_LEN + c4 * 4] = z;
        }
        return;
    }

    const int w = tid >> 6, l = tid & 63, lm = l & 15, quad = l >> 4;
    __shared__ __align__(16) short Qs[64][72];
    __shared__ __align__(16) short Ks[64][72];
    __shared__ float padf[64];

#pragma unroll
    for (int i = 0; i < 2; ++i) {
        int idx = tid + i * 256;
        int r = idx >> 3, c8 = idx & 7;
        *(int4*)&Qs[r][c8 * 8] =
            *(const int4*)&QKV[((size_t)(b * S_LEN + q0 + r)) * QKVN + h * DK + c8 * 8];
        *(int4*)&Ks[r][c8 * 8] =
            *(const int4*)&QKV[((size_t)(b * S_LEN + k0 + r)) * QKVN + 1024 + h * DK + c8 * 8];
    }
    if (tid < 64) padf[tid] = (tok[b * S_LEN + k0 + tid] == 0) ? 1.f : 0.f;
    __syncthreads();

    float rp[4] = {0.f, 0.f, 0.f, 0.f};
#pragma unroll
    for (int nt = 0; nt < 4; ++nt) {
        f32x4 acc = {0.f, 0.f, 0.f, 0.f};
#pragma unroll
        for (int kc = 0; kc < 2; ++kc) {
            bf16x8 a = *(const bf16x8*)&Qs[w * 16 + lm][kc * 32 + quad * 8];
            bf16x8 bb = *(const bf16x8*)&Ks[nt * 16 + lm][kc * 32 + quad * 8];
            acc = mfma16(a, bb, acc);
        }
        int kcol = k0 + nt * 16 + lm;
        bool pad = padf[nt * 16 + lm] != 0.f;
#pragma unroll
        for (int r = 0; r < 4; ++r) {
            int qrow = q0 + w * 16 + quad * 4 + r;
            bool msk = pad || (kcol > qrow);
            rp[r] += msk ? 0.f : __expf(acc[r] * 0.125f - SM_SHIFT);
        }
    }
#pragma unroll
    for (int off = 1; off < 16; off <<= 1)
#pragma unroll
        for (int r = 0; r < 4; ++r) rp[r] += __shfl_xor(rp[r], off);

    if (lm == 0) {
#pragma unroll
        for (int r = 0; r < 4; ++r)
            atomicAdd(&Lrow[(size_t)bh * S_LEN + q0 + w * 16 + quad * 4 + r], rp[r]);
    }
}

// ---------------------------------------------------------------------------
// Pass B: p = exp(s-8)/l, write fp32 attn (causal band, normalized, once),
// P -> LDS bf16 -> MFMA P@V -> ctx bf16. (R5-verified serial form.)
// ---------------------------------------------------------------------------
__global__ __launch_bounds__(256) void flash_pb(
    const short* __restrict__ QKV, const short* __restrict__ Vt,
    const int* __restrict__ tok, const float* __restrict__ Lrow,
    float* __restrict__ attn, short* __restrict__ ctxb) {
    const int bh = blockIdx.y, b = bh >> 4, h = bh & 15;
    const int qt = blockIdx.x, q0 = qt * 64;
    const int tid = threadIdx.x;
    const int w = tid >> 6, l = tid & 63, lm = l & 15, quad = l >> 4;
    __shared__ __align__(16) short Qs[64][72];
    __shared__ __align__(16) short Ks[64][72];
    __shared__ __align__(16) short Vs[64][72];
    __shared__ __align__(16) short Ps[64][72];
    __shared__ float padf[64];

#pragma unroll
    for (int i = 0; i < 2; ++i) {
        int idx = tid + i * 256;
        int r = idx >> 3, c8 = idx & 7;
        *(int4*)&Qs[r][c8 * 8] =
            *(const int4*)&QKV[((size_t)(b * S_LEN + q0 + r)) * QKVN + h * DK + c8 * 8];
    }

    float linv[4];
#pragma unroll
    for (int r = 0; r < 4; ++r)
        linv[r] = 1.f / Lrow[(size_t)bh * S_LEN + q0 + w * 16 + quad * 4 + r];

    f32x4 oacc[4] = {};

    for (int kt = 0; kt <= qt; ++kt) {
        __syncthreads();
#pragma unroll
        for (int i = 0; i < 2; ++i) {
            int idx = tid + i * 256;
            int r = idx >> 3, c8 = idx & 7;
            *(int4*)&Ks[r][c8 * 8] =
                *(const int4*)&QKV[((size_t)(b * S_LEN + kt * 64 + r)) * QKVN + 1024 + h * DK + c8 * 8];
            *(int4*)&Vs[r][c8 * 8] =
                *(const int4*)&Vt[((size_t)(bh * DK + r)) * S_LEN + kt * 64 + c8 * 8];
        }
        if (tid < 64) padf[tid] = (tok[b * S_LEN + kt * 64 + tid] == 0) ? 1.f : 0.f;
        __syncthreads();

#pragma unroll
        for (int nt = 0; nt < 4; ++nt) {
            f32x4 acc = {0.f, 0.f, 0.f, 0.f};
#pragma unroll
            for (int kc = 0; kc < 2; ++kc) {
                bf16x8 a = *(const bf16x8*)&Qs[w * 16 + lm][kc * 32 + quad * 8];
                bf16x8 bb = *(const bf16x8*)&Ks[nt * 16 + lm][kc * 32 + quad * 8];
                acc = mfma16(a, bb, acc);
            }
            int kcol = kt * 64 + nt * 16 + lm;
            bool pad = padf[nt * 16 + lm] != 0.f;
#pragma unroll
            for (int r = 0; r < 4; ++r) {
                int qrow = q0 + w * 16 + quad * 4 + r;
                bool msk = pad || (kcol > qrow);
                float p = msk ? 0.f : __expf(acc[r] * 0.125f - SM_SHIFT) * linv[r];
                attn[((size_t)bh * S_LEN + qrow) * S_LEN + kcol] = p;
                Ps[w * 16 + quad * 4 + r][nt * 16 + lm] = f2bf(p);
            }
        }
        // P (written by this wave's own lanes) -> A-frags; V -> B-frags
#pragma unroll
        for (int kc = 0; kc < 2; ++kc) {
            bf16x8 a = *(const bf16x8*)&Ps[w * 16 + lm][kc * 32 + quad * 8];
#pragma unroll
            for (int dt = 0; dt < 4; ++dt) {
                bf16x8 bv = *(const bf16x8*)&Vs[dt * 16 + lm][kc * 32 + quad * 8];
                oacc[dt] = mfma16(a, bv, oacc[dt]);
            }
        }
    }

#pragma unroll
    for (int dt = 0; dt < 4; ++dt)
#pragma unroll
        for (int r = 0; r < 4; ++r) {
            int qrow = q0 + w * 16 + quad * 4 + r;
            ctxb[((size_t)(b * S_LEN + qrow)) * DMODEL + h * DK + dt * 16 + lm] =
                f2bf(oacc[dt][r]);
        }
}

// ---------------------------------------------------------------------------
// Fully-masked rows (q < first-nonpad): attn row = 1/2048 (all heads),
// ctx row = mean(V). Rare/usually-empty; blocks early-out.
// ---------------------------------------------------------------------------
__global__ __launch_bounds__(256) void fix_fullmask(
    const int* __restrict__ fnp, const short* __restrict__ QKV,
    float* __restrict__ attn, short* __restrict__ ctxb) {
    const int b = blockIdx.x >> 11, q = blockIdx.x & 2047;
    if (q >= fnp[b]) return;
    const float u = 1.f / (float)S_LEN;
    float4 uu = {u, u, u, u};
    for (int i = threadIdx.x; i < NH * (S_LEN / 4); i += 256) {
        int h = i / (S_LEN / 4), c4 = i % (S_LEN / 4);
        *(float4*)&attn[(((size_t)(b * NH + h) * S_LEN + q)) * S_LEN + c4 * 4] = uu;
    }
    for (int d = threadIdx.x; d < DMODEL; d += 256) {
        float sv = 0.f;
        for (int s = 0; s < S_LEN; ++s)
            sv += bf2f(QKV[((size_t)(b * S_LEN + s)) * QKVN + 2048 + d]);
        ctxb[((size_t)(b * S_LEN + q)) * DMODEL + d] = f2bf(sv * u);
    }
}

extern "C" void kernel_launch(void* const* d_in, const int* in_sizes, int n_in,
                              void* d_out, int out_size, void* d_ws, size_t ws_size,
                              hipStream_t stream) {
    const float* x  = (const float*)d_in[0];
    const int*  tok = (const int*)d_in[1];
    const float* wq = (const float*)d_in[2];
    const float* bq = (const float*)d_in[3];
    const float* wk = (const float*)d_in[4];
    const float* bk = (const float*)d_in[5];
    const float* wv = (const float*)d_in[6];
    const float* bv = (const float*)d_in[7];
    const float* wo = (const float*)d_in[8];
    const float* bo = (const float*)d_in[9];

    float* out  = (float*)d_out;
    float* attn = out + (size_t)B_SZ * S_LEN * DMODEL;

    const size_t NTOK = (size_t)B_SZ * S_LEN;        // 4096
    const size_t NE   = NTOK * DMODEL;               // 4,194,304
    const size_t WSZ  = (size_t)DMODEL * DMODEL;     // 1M elements
    short* xb    = (short*)d_ws;                     // [4096][1024] bf16
    short* Wt3   = xb + NE;                          // [3072][1024] bf16
    short* Wto   = Wt3 + 3 * WSZ;                    // [1024][1024] bf16
    short* QKVb  = Wto + WSZ;                        // [4096][3072] bf16
    short* Vt    = QKVb + NTOK * QKVN;               // [32][64][2048] bf16
    short* ctxb  = Vt + NE;                          // [4096][1024] bf16
    float* cbias = (float*)(ctxb + NE);              // [3072]
    float* Lrow  = cbias + QKVN;                     // [32][2048]
    int*   fnp   = (int*)(Lrow + (size_t)B_SZ * NH * S_LEN);

    dim3 blk(256);

    prep<<<dim3(PREP_NBLK), blk, 0, stream>>>(x, wq, wk, wv, wo, bq, bk, bv, tok,
                                              xb, Wt3, Wto, cbias, Lrow, fnp);

    gemm128<<<dim3(QKVN / 128, (int)(NTOK / 128)), blk, 0, stream>>>(
        xb, Wt3, cbias, QKVb, (int)NTOK, QKVN, DMODEL);

    vtrans<<<dim3(S_LEN / 64, B_SZ * NH), blk, 0, stream>>>(QKVb, Vt);

    lsum_par<<<dim3((S_LEN / 64) * (S_LEN / 64), B_SZ * NH), blk, 0, stream>>>(
        QKVb, tok, Lrow, attn);

    flash_pb<<<dim3(S_LEN / 64, B_SZ * NH), blk, 0, stream>>>(QKVb, Vt, tok, Lrow,
                                                              attn, ctxb);

    fix_fullmask<<<dim3(B_SZ * S_LEN), blk, 0, stream>>>(fnp, QKVb, attn, ctxb);

    gemm_out128f<<<dim3(DMODEL / 128, (int)(NTOK / 128)), blk, 0, stream>>>(
        ctxb, Wto, bo, out, (int)NTOK, DMODEL, DMODEL);
}